// Round 1
// baseline (6974.795 us; speedup 1.0000x reference)
//
#include <hip/hip_runtime.h>

#define LIST_CAP 65536

// ---------------- pass A: in-degree over dst ----------------
__global__ void k_deg(const int* __restrict__ dst, int E, unsigned int* __restrict__ deg) {
    int stride = gridDim.x * blockDim.x;
    for (int e = blockIdx.x * blockDim.x + threadIdx.x; e < E; e += stride) {
        atomicAdd(&deg[dst[e]], 1u);
    }
}

// ---------------- pass B: dinv + hW1 = x @ W1 ----------------
__global__ void k_node1(const float* __restrict__ x, const float* __restrict__ W1,
                        unsigned int* __restrict__ deg_dinv, float* __restrict__ hW, int N) {
    int i = blockIdx.x * blockDim.x + threadIdx.x;
    if (i >= N) return;
    float d = (float)(deg_dinv[i] + 1u);      // +1 self-loop
    float dinv = rsqrtf(d);
    ((float*)deg_dinv)[i] = dinv;             // overwrite deg with dinv (same slot)
    const float4 xv = *(const float4*)(x + (size_t)i * 4);
    float w[16];
#pragma unroll
    for (int k = 0; k < 16; k++) w[k] = W1[k];
    float4 o;
    o.x = xv.x * w[0] + xv.y * w[4] + xv.z * w[8]  + xv.w * w[12];
    o.y = xv.x * w[1] + xv.y * w[5] + xv.z * w[9]  + xv.w * w[13];
    o.z = xv.x * w[2] + xv.y * w[6] + xv.z * w[10] + xv.w * w[14];
    o.w = xv.x * w[3] + xv.y * w[7] + xv.z * w[11] + xv.w * w[15];
    *(float4*)(hW + (size_t)i * 4) = o;
}

// ---------------- scatter: acc[dst] += hW[src] * dinv[src]*dinv[dst] ----------------
__global__ void k_scatter(const int* __restrict__ src, const int* __restrict__ dst, int E,
                          const float* __restrict__ dinv, const float* __restrict__ hW,
                          float* __restrict__ acc) {
    int stride = gridDim.x * blockDim.x;
    for (int e = blockIdx.x * blockDim.x + threadIdx.x; e < E; e += stride) {
        int s = src[e], d = dst[e];
        float nrm = dinv[s] * dinv[d];
        float4 h = *(const float4*)(hW + (size_t)s * 4);
        float* a = acc + (size_t)d * 4;
        atomicAdd(a + 0, h.x * nrm);
        atomicAdd(a + 1, h.y * nrm);
        atomicAdd(a + 2, h.z * nrm);
        atomicAdd(a + 3, h.w * nrm);
    }
}

// ---------------- pass D: h1 = relu(conv1), hW <- h1 @ W2 (in place) ----------------
__global__ void k_node2(const float* __restrict__ acc, const float* __restrict__ dinv,
                        const float* __restrict__ b1, const float* __restrict__ W2,
                        float* __restrict__ hW, int N) {
    int i = blockIdx.x * blockDim.x + threadIdx.x;
    if (i >= N) return;
    float di = dinv[i];
    float di2 = di * di;
    float4 a  = *(const float4*)(acc + (size_t)i * 4);
    float4 hw = *(const float4*)(hW + (size_t)i * 4);
    float h0 = fmaxf(a.x + hw.x * di2 + b1[0], 0.f);
    float h1 = fmaxf(a.y + hw.y * di2 + b1[1], 0.f);
    float h2 = fmaxf(a.z + hw.z * di2 + b1[2], 0.f);
    float h3 = fmaxf(a.w + hw.w * di2 + b1[3], 0.f);
    float w[16];
#pragma unroll
    for (int k = 0; k < 16; k++) w[k] = W2[k];
    float4 o;
    o.x = h0 * w[0] + h1 * w[4] + h2 * w[8]  + h3 * w[12];
    o.y = h0 * w[1] + h1 * w[5] + h2 * w[9]  + h3 * w[13];
    o.z = h0 * w[2] + h1 * w[6] + h2 * w[10] + h3 * w[14];
    o.w = h0 * w[3] + h1 * w[7] + h2 * w[11] + h3 * w[15];
    *(float4*)(hW + (size_t)i * 4) = o;
}

// ---------------- pass F: h2 = relu(conv2), z = h2 @ Wr + br ----------------
__global__ void k_node3(const float* __restrict__ acc, const float* __restrict__ dinv,
                        const float* __restrict__ b2, const float* __restrict__ Wr,
                        const float* __restrict__ br, const float* __restrict__ hW,
                        float* __restrict__ z, int N) {
    int i = blockIdx.x * blockDim.x + threadIdx.x;
    if (i >= N) return;
    float di = dinv[i];
    float di2 = di * di;
    float4 a  = *(const float4*)(acc + (size_t)i * 4);
    float4 hw = *(const float4*)(hW + (size_t)i * 4);
    float h0 = fmaxf(a.x + hw.x * di2 + b2[0], 0.f);
    float h1 = fmaxf(a.y + hw.y * di2 + b2[1], 0.f);
    float h2 = fmaxf(a.z + hw.z * di2 + b2[2], 0.f);
    float h3 = fmaxf(a.w + hw.w * di2 + b2[3], 0.f);
    z[i] = h0 * Wr[0] + h1 * Wr[1] + h2 * Wr[2] + h3 * Wr[3] + br[0];
}

// ---------------- pass G1: default outputs + compact masked edges ----------------
__global__ void k_final(const int* __restrict__ src, const int* __restrict__ dst, int E,
                        const int* __restrict__ nodep, const float* __restrict__ z,
                        float* __restrict__ out_score, float* __restrict__ out_tgt,
                        int* __restrict__ cnt, int* __restrict__ le, int* __restrict__ lt,
                        float* __restrict__ ll) {
    int node = *nodep;
    int stride = gridDim.x * blockDim.x;
    for (int e = blockIdx.x * blockDim.x + threadIdx.x; e < E; e += stride) {
        int s = src[e], d = dst[e];
        if (s == node || d == node) {
            int t = (s == node) ? d : s;
            int pos = atomicAdd(cnt, 1);
            if (pos < LIST_CAP) {
                le[pos] = e;
                lt[pos] = t;
                ll[pos] = z[t];
            }
        }
        out_score[e] = 0.f;
        out_tgt[e]  = -1.f;
    }
}

// ---------------- pass G2: tiny softmax over compacted list ----------------
__global__ void k_softmax(const int* __restrict__ cnt, const int* __restrict__ le,
                          const int* __restrict__ lt, const float* __restrict__ ll,
                          float* __restrict__ out_score, float* __restrict__ out_tgt) {
    if (blockIdx.x != 0 || threadIdx.x != 0) return;
    int n = *cnt;
    if (n > LIST_CAP) n = LIST_CAP;
    float m = -3.402823466e+38f;
    for (int k = 0; k < n; k++) m = fmaxf(m, ll[k]);
    float ssum = 0.f;
    for (int k = 0; k < n; k++) ssum += __expf(ll[k] - m);
    float inv = (ssum > 0.f) ? 1.f / ssum : 0.f;
    for (int k = 0; k < n; k++) {
        out_score[le[k]] = __expf(ll[k] - m) * inv;
        out_tgt[le[k]]   = (float)lt[k];
    }
}

extern "C" void kernel_launch(void* const* d_in, const int* in_sizes, int n_in,
                              void* d_out, int out_size, void* d_ws, size_t ws_size,
                              hipStream_t stream) {
    const float* x  = (const float*)d_in[0];
    const int*   ei = (const int*)d_in[1];
    const int*   nodep = (const int*)d_in[2];
    const float* W1 = (const float*)d_in[3];
    const float* b1 = (const float*)d_in[4];
    const float* W2 = (const float*)d_in[5];
    const float* b2 = (const float*)d_in[6];
    const float* Wr = (const float*)d_in[7];
    const float* br = (const float*)d_in[8];

    const int N = in_sizes[0] / 4;
    const int E = in_sizes[1] / 2;
    const int* src = ei;
    const int* dst = ei + E;

    // workspace layout (all 16B-aligned for N=500000)
    char* ws = (char*)d_ws;
    unsigned int* deg_dinv = (unsigned int*)ws;               // N*4  (deg, then dinv)
    float* hW  = (float*)(ws + (size_t)N * 4);                // N*16 (hW1, then hW2)
    float* acc = (float*)(ws + (size_t)N * 20);               // N*16
    float* z   = (float*)(ws + (size_t)N * 36);               // N*4
    int*   cnt = (int*)(ws + (size_t)N * 40);                 // 16 (padded)
    int*   le  = cnt + 4;                                     // LIST_CAP*4
    int*   lt  = le + LIST_CAP;                               // LIST_CAP*4
    float* ll  = (float*)(lt + LIST_CAP);                     // LIST_CAP*4

    float* out_score = (float*)d_out;
    float* out_tgt   = out_score + E;

    const int TB = 256;
    const int nodeBlocks = (N + TB - 1) / TB;
    int edgeBlocks = (E + TB - 1) / TB;
    if (edgeBlocks > 8192) edgeBlocks = 8192;

    hipMemsetAsync(deg_dinv, 0, (size_t)N * 4, stream);
    hipMemsetAsync(acc, 0, (size_t)N * 16, stream);
    hipMemsetAsync(cnt, 0, 4, stream);

    k_deg<<<edgeBlocks, TB, 0, stream>>>(dst, E, deg_dinv);
    k_node1<<<nodeBlocks, TB, 0, stream>>>(x, W1, deg_dinv, hW, N);
    k_scatter<<<edgeBlocks, TB, 0, stream>>>(src, dst, E, (const float*)deg_dinv, hW, acc);
    k_node2<<<nodeBlocks, TB, 0, stream>>>(acc, (const float*)deg_dinv, b1, W2, hW, N);
    hipMemsetAsync(acc, 0, (size_t)N * 16, stream);
    k_scatter<<<edgeBlocks, TB, 0, stream>>>(src, dst, E, (const float*)deg_dinv, hW, acc);
    k_node3<<<nodeBlocks, TB, 0, stream>>>(acc, (const float*)deg_dinv, b2, Wr, br, hW, z, N);
    k_final<<<edgeBlocks, TB, 0, stream>>>(src, dst, E, nodep, z, out_score, out_tgt,
                                           cnt, le, lt, ll);
    k_softmax<<<1, 64, 0, stream>>>(cnt, le, lt, ll, out_score, out_tgt);
}

// Round 2
// 2935.678 us; speedup vs baseline: 2.3759x; 2.3759x over previous
//
#include <hip/hip_runtime.h>

#define LIST_CAP 65536

// ---------------- pass 1: in-degree over dst (int atomics, vec4) ----------------
__global__ void k_deg(const int4* __restrict__ dst4, int nvec, int* __restrict__ deg) {
    int stride = gridDim.x * blockDim.x;
    for (int v = blockIdx.x * blockDim.x + threadIdx.x; v < nvec; v += stride) {
        int4 d = dst4[v];
        atomicAdd(&deg[d.x], 1);
        atomicAdd(&deg[d.y], 1);
        atomicAdd(&deg[d.z], 1);
        atomicAdd(&deg[d.w], 1);
    }
}

// ---------------- scan phase A: per-1024-chunk sums ----------------
__global__ void k_scanA(const int* __restrict__ deg, int* __restrict__ blockSums, int N) {
    __shared__ int lds[256];
    int b = blockIdx.x, t = threadIdx.x;
    int base = b * 1024 + t * 4;
    int s = 0;
#pragma unroll
    for (int k = 0; k < 4; k++) { int idx = base + k; if (idx < N) s += deg[idx]; }
    lds[t] = s; __syncthreads();
    for (int off = 128; off > 0; off >>= 1) {
        if (t < off) lds[t] += lds[t + off];
        __syncthreads();
    }
    if (t == 0) blockSums[b] = lds[0];
}

// ---------------- scan phase B: scan of chunk sums (NB <= 512) ----------------
__global__ void k_scanB(int* __restrict__ blockSums, int NB, int* __restrict__ row_ptr, int N) {
    __shared__ int lds[512];
    int t = threadIdx.x;
    int v = (t < NB) ? blockSums[t] : 0;
    lds[t] = v; __syncthreads();
    for (int off = 1; off < 512; off <<= 1) {
        int x = (t >= off) ? lds[t - off] : 0;
        __syncthreads();
        lds[t] += x;
        __syncthreads();
    }
    if (t < NB) blockSums[t] = lds[t] - v;     // exclusive offsets
    if (t == NB - 1) row_ptr[N] = lds[t];      // total == E
}

// ---------------- scan phase C: row_ptr + cursor + dinv; cursor aliases deg ----------------
__global__ void k_scanC(int* __restrict__ deg_cursor, const int* __restrict__ blockSums,
                        int* __restrict__ row_ptr, float* __restrict__ dinv, int N) {
    __shared__ int lds[256];
    int b = blockIdx.x, t = threadIdx.x;
    int base = b * 1024 + t * 4;
    int v[4]; int s = 0;
#pragma unroll
    for (int k = 0; k < 4; k++) {
        int idx = base + k;
        v[k] = (idx < N) ? deg_cursor[idx] : 0;
        s += v[k];
    }
    lds[t] = s; __syncthreads();
    for (int off = 1; off < 256; off <<= 1) {
        int x = (t >= off) ? lds[t - off] : 0;
        __syncthreads();
        lds[t] += x;
        __syncthreads();
    }
    int run = blockSums[b] + (lds[t] - s);
#pragma unroll
    for (int k = 0; k < 4; k++) {
        int idx = base + k;
        if (idx < N) {
            row_ptr[idx] = run;
            deg_cursor[idx] = run;                         // fill cursor
            dinv[idx] = rsqrtf((float)(v[k] + 1));         // +1 self-loop
            run += v[k];
        }
    }
}

// ---------------- pass 2: counting-sort fill of CSR ----------------
__global__ void k_fill(const int4* __restrict__ src4, const int4* __restrict__ dst4, int nvec,
                       int* __restrict__ cursor, int* __restrict__ csr_src) {
    int stride = gridDim.x * blockDim.x;
    for (int v = blockIdx.x * blockDim.x + threadIdx.x; v < nvec; v += stride) {
        int4 s = src4[v];
        int4 d = dst4[v];
        csr_src[atomicAdd(&cursor[d.x], 1)] = s.x;
        csr_src[atomicAdd(&cursor[d.y], 1)] = s.y;
        csr_src[atomicAdd(&cursor[d.z], 1)] = s.z;
        csr_src[atomicAdd(&cursor[d.w], 1)] = s.w;
    }
}

// ---------------- node pass: g1 = (x @ W1) * dinv ----------------
__global__ void k_node1(const float* __restrict__ x, const float* __restrict__ W1,
                        const float* __restrict__ dinv, float* __restrict__ g, int N) {
    int i = blockIdx.x * blockDim.x + threadIdx.x;
    if (i >= N) return;
    const float4 xv = *(const float4*)(x + (size_t)i * 4);
    float di = dinv[i];
    float w[16];
#pragma unroll
    for (int k = 0; k < 16; k++) w[k] = W1[k];
    float4 o;
    o.x = (xv.x * w[0] + xv.y * w[4] + xv.z * w[8]  + xv.w * w[12]) * di;
    o.y = (xv.x * w[1] + xv.y * w[5] + xv.z * w[9]  + xv.w * w[13]) * di;
    o.z = (xv.x * w[2] + xv.y * w[6] + xv.z * w[10] + xv.w * w[14]) * di;
    o.w = (xv.x * w[3] + xv.y * w[7] + xv.z * w[11] + xv.w * w[15]) * di;
    *(float4*)(g + (size_t)i * 4) = o;
}

__device__ __forceinline__ float4 gather_sum(int i, const int* __restrict__ rp,
                                             const int* __restrict__ csr,
                                             const float* __restrict__ g) {
    float4 s = *(const float4*)(g + (size_t)i * 4);   // self-loop term
    int b = rp[i], e = rp[i + 1];
    for (int j = b; j < e; j++) {
        int n = csr[j];
        const float4 h = *(const float4*)(g + (size_t)n * 4);
        s.x += h.x; s.y += h.y; s.z += h.z; s.w += h.w;
    }
    return s;
}

// ---------------- conv1 gather + fused (relu, @W2, *dinv) epilogue ----------------
__global__ void k_gather1(const int* __restrict__ rp, const int* __restrict__ csr,
                          const float* __restrict__ gA, const float* __restrict__ dinv,
                          const float* __restrict__ b1, const float* __restrict__ W2,
                          float* __restrict__ gB, int N) {
    int i = blockIdx.x * blockDim.x + threadIdx.x;
    if (i >= N) return;
    float di = dinv[i];
    float4 s = gather_sum(i, rp, csr, gA);
    float h0 = fmaxf(s.x * di + b1[0], 0.f);
    float h1 = fmaxf(s.y * di + b1[1], 0.f);
    float h2 = fmaxf(s.z * di + b1[2], 0.f);
    float h3 = fmaxf(s.w * di + b1[3], 0.f);
    float w[16];
#pragma unroll
    for (int k = 0; k < 16; k++) w[k] = W2[k];
    float4 o;
    o.x = (h0 * w[0] + h1 * w[4] + h2 * w[8]  + h3 * w[12]) * di;
    o.y = (h0 * w[1] + h1 * w[5] + h2 * w[9]  + h3 * w[13]) * di;
    o.z = (h0 * w[2] + h1 * w[6] + h2 * w[10] + h3 * w[14]) * di;
    o.w = (h0 * w[3] + h1 * w[7] + h2 * w[11] + h3 * w[15]) * di;
    *(float4*)(gB + (size_t)i * 4) = o;
}

// ---------------- conv2 gather + fused (relu, @Wr) epilogue -> z ----------------
__global__ void k_gather2(const int* __restrict__ rp, const int* __restrict__ csr,
                          const float* __restrict__ gB, const float* __restrict__ dinv,
                          const float* __restrict__ b2, const float* __restrict__ Wr,
                          const float* __restrict__ br, float* __restrict__ z, int N) {
    int i = blockIdx.x * blockDim.x + threadIdx.x;
    if (i >= N) return;
    float di = dinv[i];
    float4 s = gather_sum(i, rp, csr, gB);
    float h0 = fmaxf(s.x * di + b2[0], 0.f);
    float h1 = fmaxf(s.y * di + b2[1], 0.f);
    float h2 = fmaxf(s.z * di + b2[2], 0.f);
    float h3 = fmaxf(s.w * di + b2[3], 0.f);
    z[i] = h0 * Wr[0] + h1 * Wr[1] + h2 * Wr[2] + h3 * Wr[3] + br[0];
}

// ---------------- final pass: default outputs + compact masked edges (vec4) ----------------
__global__ void k_final(const int4* __restrict__ src4, const int4* __restrict__ dst4, int nvec,
                        const int* __restrict__ nodep, const float* __restrict__ z,
                        float4* __restrict__ out_score4, float4* __restrict__ out_tgt4,
                        int* __restrict__ cnt, int* __restrict__ le, int* __restrict__ lt,
                        float* __restrict__ ll) {
    int node = *nodep;
    int stride = gridDim.x * blockDim.x;
    const float4 zero = make_float4(0.f, 0.f, 0.f, 0.f);
    const float4 neg1 = make_float4(-1.f, -1.f, -1.f, -1.f);
    for (int v = blockIdx.x * blockDim.x + threadIdx.x; v < nvec; v += stride) {
        int4 s = src4[v];
        int4 d = dst4[v];
        out_score4[v] = zero;
        out_tgt4[v] = neg1;
        int ss[4] = {s.x, s.y, s.z, s.w};
        int dd[4] = {d.x, d.y, d.z, d.w};
#pragma unroll
        for (int k = 0; k < 4; k++) {
            if (ss[k] == node || dd[k] == node) {
                int t = (ss[k] == node) ? dd[k] : ss[k];
                int pos = atomicAdd(cnt, 1);
                if (pos < LIST_CAP) {
                    le[pos] = v * 4 + k;
                    lt[pos] = t;
                    ll[pos] = z[t];
                }
            }
        }
    }
}

// ---------------- tiny softmax over compacted list ----------------
__global__ void k_softmax(const int* __restrict__ cnt, const int* __restrict__ le,
                          const int* __restrict__ lt, const float* __restrict__ ll,
                          float* __restrict__ out_score, float* __restrict__ out_tgt) {
    if (blockIdx.x != 0 || threadIdx.x != 0) return;
    int n = *cnt;
    if (n > LIST_CAP) n = LIST_CAP;
    float m = -3.402823466e+38f;
    for (int k = 0; k < n; k++) m = fmaxf(m, ll[k]);
    float ssum = 0.f;
    for (int k = 0; k < n; k++) ssum += __expf(ll[k] - m);
    float inv = (ssum > 0.f) ? 1.f / ssum : 0.f;
    for (int k = 0; k < n; k++) {
        out_score[le[k]] = __expf(ll[k] - m) * inv;
        out_tgt[le[k]]   = (float)lt[k];
    }
}

extern "C" void kernel_launch(void* const* d_in, const int* in_sizes, int n_in,
                              void* d_out, int out_size, void* d_ws, size_t ws_size,
                              hipStream_t stream) {
    const float* x  = (const float*)d_in[0];
    const int*   ei = (const int*)d_in[1];
    const int*   nodep = (const int*)d_in[2];
    const float* W1 = (const float*)d_in[3];
    const float* b1 = (const float*)d_in[4];
    const float* W2 = (const float*)d_in[5];
    const float* b2 = (const float*)d_in[6];
    const float* Wr = (const float*)d_in[7];
    const float* br = (const float*)d_in[8];

    const int N = in_sizes[0] / 4;
    const int E = in_sizes[1] / 2;
    const int nvec = E / 4;
    const int* src = ei;
    const int* dst = ei + E;

    // workspace layout (256B-aligned segments)
    char* ws = (char*)d_ws;
    size_t off = 0;
    auto alloc = [&](size_t bytes) { char* p = ws + off; off = (off + bytes + 255) & ~(size_t)255; return p; };
    int*   row_ptr   = (int*)  alloc((size_t)(N + 1) * 4);
    int*   deg_cur   = (int*)  alloc((size_t)N * 4);       // deg, then fill cursor
    float* dinv      = (float*)alloc((size_t)N * 4);
    float* gA        = (float*)alloc((size_t)N * 16);
    float* gB        = (float*)alloc((size_t)N * 16);
    float* z         = (float*)alloc((size_t)N * 4);
    int*   blockSums = (int*)  alloc(4096);
    int*   cnt       = (int*)  alloc(256);
    int*   le        = (int*)  alloc((size_t)LIST_CAP * 4);
    int*   lt        = (int*)  alloc((size_t)LIST_CAP * 4);
    float* ll        = (float*)alloc((size_t)LIST_CAP * 4);
    int*   csr_src   = (int*)  alloc((size_t)E * 4);

    float* out_score = (float*)d_out;
    float* out_tgt   = out_score + E;

    const int TB = 256;
    const int nodeBlocks = (N + TB - 1) / TB;
    const int NB = (N + 1023) / 1024;                      // scan chunks (<=512)
    int edgeBlocks = (nvec + TB - 1) / TB;
    if (edgeBlocks > 4096) edgeBlocks = 4096;

    hipMemsetAsync(deg_cur, 0, (size_t)N * 4, stream);
    hipMemsetAsync(cnt, 0, 4, stream);

    k_deg<<<edgeBlocks, TB, 0, stream>>>((const int4*)dst, nvec, deg_cur);
    k_scanA<<<NB, TB, 0, stream>>>(deg_cur, blockSums, N);
    k_scanB<<<1, 512, 0, stream>>>(blockSums, NB, row_ptr, N);
    k_scanC<<<NB, TB, 0, stream>>>(deg_cur, blockSums, row_ptr, dinv, N);
    k_fill<<<edgeBlocks, TB, 0, stream>>>((const int4*)src, (const int4*)dst, nvec,
                                          deg_cur, csr_src);
    k_node1<<<nodeBlocks, TB, 0, stream>>>(x, W1, dinv, gA, N);
    k_gather1<<<nodeBlocks, TB, 0, stream>>>(row_ptr, csr_src, gA, dinv, b1, W2, gB, N);
    k_gather2<<<nodeBlocks, TB, 0, stream>>>(row_ptr, csr_src, gB, dinv, b2, Wr, br, z, N);
    k_final<<<edgeBlocks, TB, 0, stream>>>((const int4*)src, (const int4*)dst, nvec, nodep, z,
                                           (float4*)out_score, (float4*)out_tgt,
                                           cnt, le, lt, ll);
    k_softmax<<<1, 64, 0, stream>>>(cnt, le, lt, ll, out_score, out_tgt);
}

// Round 3
// 911.036 us; speedup vs baseline: 7.6559x; 3.2224x over previous
//
#include <hip/hip_runtime.h>

#define CAP_I   65536        // incident edges (expected ~64)
#define CAP_S1  (1 << 18)    // S1 nodes (expected ~2K)
#define CAP_L2  (1 << 20)    // edges into T (expected ~2K)
#define CAP_L1  (1 << 22)    // edges into S1 (expected ~64K)

// ---- pass A: stream src+dst, write default outputs, collect incident edges ----
__global__ void k_passA(const int4* __restrict__ src4, const int4* __restrict__ dst4, int nvec,
                        const int* __restrict__ nodep,
                        float4* __restrict__ out_score4, float4* __restrict__ out_tgt4,
                        int* __restrict__ cnts, int* __restrict__ le, int* __restrict__ lt) {
    int node = *nodep;
    int stride = gridDim.x * blockDim.x;
    const float4 zero = make_float4(0.f, 0.f, 0.f, 0.f);
    const float4 neg1 = make_float4(-1.f, -1.f, -1.f, -1.f);
    for (int v = blockIdx.x * blockDim.x + threadIdx.x; v < nvec; v += stride) {
        int4 s4 = src4[v];
        int4 d4 = dst4[v];
        out_score4[v] = zero;
        out_tgt4[v]   = neg1;
        int ss[4] = {s4.x, s4.y, s4.z, s4.w};
        int dd[4] = {d4.x, d4.y, d4.z, d4.w};
#pragma unroll
        for (int k = 0; k < 4; k++) {
            if (ss[k] == node || dd[k] == node) {
                int t = (ss[k] == node) ? dd[k] : ss[k];
                int pos = atomicAdd(&cnts[0], 1);
                if (pos < CAP_I) { le[pos] = v * 4 + k; lt[pos] = t; }
            }
        }
    }
}

// ---- mark T, seed S1/S0 with T ----
__global__ void k_markT(const int* __restrict__ cnts, const int* __restrict__ lt,
                        unsigned char* __restrict__ flagT, unsigned char* __restrict__ flagS1,
                        unsigned char* __restrict__ flagS0,
                        int* __restrict__ cnts_w, int* __restrict__ s1list) {
    int n = cnts[0]; if (n > CAP_I) n = CAP_I;
    for (int i = threadIdx.x; i < n; i += blockDim.x) {
        int t = lt[i];
        flagT[t] = 1; flagS0[t] = 1;
        if (!flagS1[t]) {                 // benign race: dup appends are harmless
            flagS1[t] = 1;
            int p = atomicAdd(&cnts_w[2], 1);
            if (p < CAP_S1) s1list[p] = t;
        }
    }
}

// ---- pass B: dst in T -> L2 edge list, srcs -> S1 ----
__global__ void k_passB(const int* __restrict__ src, const int4* __restrict__ dst4, int nvec,
                        const unsigned char* __restrict__ flagT,
                        unsigned char* __restrict__ flagS1, unsigned char* __restrict__ flagS0,
                        int* __restrict__ cnts, int* __restrict__ l2s, int* __restrict__ l2t,
                        int* __restrict__ s1list) {
    int stride = gridDim.x * blockDim.x;
    for (int v = blockIdx.x * blockDim.x + threadIdx.x; v < nvec; v += stride) {
        int4 d4 = dst4[v];
        int dd[4] = {d4.x, d4.y, d4.z, d4.w};
#pragma unroll
        for (int k = 0; k < 4; k++) {
            int d = dd[k];
            if (flagT[d]) {
                int s = src[v * 4 + k];
                int pos = atomicAdd(&cnts[1], 1);
                if (pos < CAP_L2) { l2s[pos] = s; l2t[pos] = d; }
                if (!flagS1[s]) {         // benign race
                    flagS1[s] = 1; flagS0[s] = 1;
                    int p = atomicAdd(&cnts[2], 1);
                    if (p < CAP_S1) s1list[p] = s;
                }
            }
        }
    }
}

// ---- pass C: dst in S1 -> L1 edge list, srcs -> S0 ----
__global__ void k_passC(const int* __restrict__ src, const int4* __restrict__ dst4, int nvec,
                        const unsigned char* __restrict__ flagS1,
                        unsigned char* __restrict__ flagS0,
                        int* __restrict__ cnts, int* __restrict__ l1s, int* __restrict__ l1t) {
    int stride = gridDim.x * blockDim.x;
    for (int v = blockIdx.x * blockDim.x + threadIdx.x; v < nvec; v += stride) {
        int4 d4 = dst4[v];
        int dd[4] = {d4.x, d4.y, d4.z, d4.w};
#pragma unroll
        for (int k = 0; k < 4; k++) {
            int d = dd[k];
            if (flagS1[d]) {
                int s = src[v * 4 + k];
                int pos = atomicAdd(&cnts[3], 1);
                if (pos < CAP_L1) { l1s[pos] = s; l1t[pos] = d; }
                flagS0[s] = 1;
            }
        }
    }
}

// ---- pass D: in-degree, restricted to S0 ----
__global__ void k_passD(const int4* __restrict__ dst4, int nvec,
                        const unsigned char* __restrict__ flagS0, int* __restrict__ deg) {
    int stride = gridDim.x * blockDim.x;
    for (int v = blockIdx.x * blockDim.x + threadIdx.x; v < nvec; v += stride) {
        int4 d4 = dst4[v];
        int dd[4] = {d4.x, d4.y, d4.z, d4.w};
#pragma unroll
        for (int k = 0; k < 4; k++) {
            int d = dd[k];
            if (flagS0[d]) atomicAdd(&deg[d], 1);
        }
    }
}

// ---- conv1 accumulation over L1: acc1[d] += (x[s]@W1)*dinv[s] ----
__global__ void k_conv1(const int* __restrict__ cnts, const int* __restrict__ l1s,
                        const int* __restrict__ l1t, const float* __restrict__ x,
                        const float* __restrict__ W1, const int* __restrict__ deg,
                        float* __restrict__ acc1) {
    int n = cnts[3]; if (n > CAP_L1) n = CAP_L1;
    int stride = gridDim.x * blockDim.x;
    for (int j = blockIdx.x * blockDim.x + threadIdx.x; j < n; j += stride) {
        int s = l1s[j], d = l1t[j];
        float4 xv = *(const float4*)(x + (size_t)s * 4);
        float dis = rsqrtf((float)deg[s] + 1.0f);
        float o0 = (xv.x * W1[0] + xv.y * W1[4] + xv.z * W1[8]  + xv.w * W1[12]) * dis;
        float o1 = (xv.x * W1[1] + xv.y * W1[5] + xv.z * W1[9]  + xv.w * W1[13]) * dis;
        float o2 = (xv.x * W1[2] + xv.y * W1[6] + xv.z * W1[10] + xv.w * W1[14]) * dis;
        float o3 = (xv.x * W1[3] + xv.y * W1[7] + xv.z * W1[11] + xv.w * W1[15]) * dis;
        float* a = acc1 + (size_t)d * 4;
        atomicAdd(a + 0, o0); atomicAdd(a + 1, o1);
        atomicAdd(a + 2, o2); atomicAdd(a + 3, o3);
    }
}

// ---- h1 epilogue over S1: gB[i] = (relu(conv1_out)@W2)*dinv[i] ----
__global__ void k_h1(const int* __restrict__ cnts, const int* __restrict__ s1list,
                     const float* __restrict__ x, const float* __restrict__ W1,
                     const float* __restrict__ b1, const float* __restrict__ W2,
                     const int* __restrict__ deg, const float* __restrict__ acc1,
                     float* __restrict__ gB) {
    int n = cnts[2]; if (n > CAP_S1) n = CAP_S1;
    int stride = gridDim.x * blockDim.x;
    for (int j = blockIdx.x * blockDim.x + threadIdx.x; j < n; j += stride) {
        int i = s1list[j];
        float di = rsqrtf((float)deg[i] + 1.0f);
        float4 xv = *(const float4*)(x + (size_t)i * 4);
        float4 a  = *(const float4*)(acc1 + (size_t)i * 4);
        float w0 = xv.x * W1[0] + xv.y * W1[4] + xv.z * W1[8]  + xv.w * W1[12];
        float w1 = xv.x * W1[1] + xv.y * W1[5] + xv.z * W1[9]  + xv.w * W1[13];
        float w2 = xv.x * W1[2] + xv.y * W1[6] + xv.z * W1[10] + xv.w * W1[14];
        float w3 = xv.x * W1[3] + xv.y * W1[7] + xv.z * W1[11] + xv.w * W1[15];
        float h0 = fmaxf((a.x + w0 * di) * di + b1[0], 0.f);
        float h1 = fmaxf((a.y + w1 * di) * di + b1[1], 0.f);
        float h2 = fmaxf((a.z + w2 * di) * di + b1[2], 0.f);
        float h3 = fmaxf((a.w + w3 * di) * di + b1[3], 0.f);
        float4 o;
        o.x = (h0 * W2[0] + h1 * W2[4] + h2 * W2[8]  + h3 * W2[12]) * di;
        o.y = (h0 * W2[1] + h1 * W2[5] + h2 * W2[9]  + h3 * W2[13]) * di;
        o.z = (h0 * W2[2] + h1 * W2[6] + h2 * W2[10] + h3 * W2[14]) * di;
        o.w = (h0 * W2[3] + h1 * W2[7] + h2 * W2[11] + h3 * W2[15]) * di;
        *(float4*)(gB + (size_t)i * 4) = o;
    }
}

// ---- conv2 accumulation over L2: acc2[t] += gB[s] ----
__global__ void k_conv2(const int* __restrict__ cnts, const int* __restrict__ l2s,
                        const int* __restrict__ l2t, const float* __restrict__ gB,
                        float* __restrict__ acc2) {
    int n = cnts[1]; if (n > CAP_L2) n = CAP_L2;
    int stride = gridDim.x * blockDim.x;
    for (int j = blockIdx.x * blockDim.x + threadIdx.x; j < n; j += stride) {
        int s = l2s[j], t = l2t[j];
        float4 g = *(const float4*)(gB + (size_t)s * 4);
        float* a = acc2 + (size_t)t * 4;
        atomicAdd(a + 0, g.x); atomicAdd(a + 1, g.y);
        atomicAdd(a + 2, g.z); atomicAdd(a + 3, g.w);
    }
}

// ---- z epilogue over incident-target list ----
__global__ void k_z(const int* __restrict__ cnts, const int* __restrict__ lt,
                    const float* __restrict__ b2, const float* __restrict__ Wr,
                    const float* __restrict__ br, const int* __restrict__ deg,
                    const float* __restrict__ acc2, const float* __restrict__ gB,
                    float* __restrict__ z) {
    int n = cnts[0]; if (n > CAP_I) n = CAP_I;
    int stride = gridDim.x * blockDim.x;
    for (int j = blockIdx.x * blockDim.x + threadIdx.x; j < n; j += stride) {
        int t = lt[j];
        float di = rsqrtf((float)deg[t] + 1.0f);
        float4 a = *(const float4*)(acc2 + (size_t)t * 4);
        float4 g = *(const float4*)(gB + (size_t)t * 4);
        float h0 = fmaxf((a.x + g.x) * di + b2[0], 0.f);
        float h1 = fmaxf((a.y + g.y) * di + b2[1], 0.f);
        float h2 = fmaxf((a.z + g.z) * di + b2[2], 0.f);
        float h3 = fmaxf((a.w + g.w) * di + b2[3], 0.f);
        z[t] = h0 * Wr[0] + h1 * Wr[1] + h2 * Wr[2] + h3 * Wr[3] + br[0];
    }
}

// ---- tiny softmax over incident edges ----
__global__ void k_softmax(const int* __restrict__ cnts, const int* __restrict__ le,
                          const int* __restrict__ lt, const float* __restrict__ z,
                          float* __restrict__ out_score, float* __restrict__ out_tgt) {
    if (blockIdx.x != 0 || threadIdx.x != 0) return;
    int n = cnts[0]; if (n > CAP_I) n = CAP_I;
    float m = -3.402823466e+38f;
    for (int k = 0; k < n; k++) m = fmaxf(m, z[lt[k]]);
    float ssum = 0.f;
    for (int k = 0; k < n; k++) ssum += __expf(z[lt[k]] - m);
    float inv = (ssum > 0.f) ? 1.f / ssum : 0.f;
    for (int k = 0; k < n; k++) {
        out_score[le[k]] = __expf(z[lt[k]] - m) * inv;
        out_tgt[le[k]]   = (float)lt[k];
    }
}

extern "C" void kernel_launch(void* const* d_in, const int* in_sizes, int n_in,
                              void* d_out, int out_size, void* d_ws, size_t ws_size,
                              hipStream_t stream) {
    const float* x  = (const float*)d_in[0];
    const int*   ei = (const int*)d_in[1];
    const int*   nodep = (const int*)d_in[2];
    const float* W1 = (const float*)d_in[3];
    const float* b1 = (const float*)d_in[4];
    const float* W2 = (const float*)d_in[5];
    const float* b2 = (const float*)d_in[6];
    const float* Wr = (const float*)d_in[7];
    const float* br = (const float*)d_in[8];

    const int N = in_sizes[0] / 4;
    const int E = in_sizes[1] / 2;
    const int nvec = E / 4;
    const int* src = ei;
    const int* dst = ei + E;

    char* ws = (char*)d_ws;
    size_t off = 0;
    auto alloc = [&](size_t bytes) { char* p = ws + off; off = (off + bytes + 255) & ~(size_t)255; return p; };
    int*   deg    = (int*)  alloc((size_t)N * 4);
    float* acc1   = (float*)alloc((size_t)N * 16);
    float* acc2   = (float*)alloc((size_t)N * 16);
    float* gB     = (float*)alloc((size_t)N * 16);
    float* z      = (float*)alloc((size_t)N * 4);
    unsigned char* flagT  = (unsigned char*)alloc(N);
    unsigned char* flagS1 = (unsigned char*)alloc(N);
    unsigned char* flagS0 = (unsigned char*)alloc(N);
    int*   cnts   = (int*)  alloc(256);                 // [0]=I [1]=L2 [2]=S1 [3]=L1
    int*   le     = (int*)  alloc((size_t)CAP_I * 4);
    int*   lt     = (int*)  alloc((size_t)CAP_I * 4);
    int*   s1list = (int*)  alloc((size_t)CAP_S1 * 4);
    int*   l2s    = (int*)  alloc((size_t)CAP_L2 * 4);
    int*   l2t    = (int*)  alloc((size_t)CAP_L2 * 4);
    int*   l1s    = (int*)  alloc((size_t)CAP_L1 * 4);
    int*   l1t    = (int*)  alloc((size_t)CAP_L1 * 4);

    float* out_score = (float*)d_out;
    float* out_tgt   = out_score + E;

    const int TB = 256;
    int edgeBlocks = (nvec + TB - 1) / TB;
    if (edgeBlocks > 2048) edgeBlocks = 2048;
    const int listBlocks = 256;

    hipMemsetAsync(deg,  0, (size_t)N * 4, stream);
    hipMemsetAsync(acc1, 0, (size_t)N * 16, stream);
    hipMemsetAsync(acc2, 0, (size_t)N * 16, stream);
    hipMemsetAsync(flagT, 0, (size_t)N * 3 + 512 + 256, stream); // flags (contiguous) + cnts
    // note: flagT..flagS0 and cnts are contiguous in ws; single memset covers them.

    k_passA<<<edgeBlocks, TB, 0, stream>>>((const int4*)src, (const int4*)dst, nvec, nodep,
                                           (float4*)out_score, (float4*)out_tgt, cnts, le, lt);
    k_markT<<<1, 256, 0, stream>>>(cnts, lt, flagT, flagS1, flagS0, cnts, s1list);
    k_passB<<<edgeBlocks, TB, 0, stream>>>(src, (const int4*)dst, nvec, flagT, flagS1, flagS0,
                                           cnts, l2s, l2t, s1list);
    k_passC<<<edgeBlocks, TB, 0, stream>>>(src, (const int4*)dst, nvec, flagS1, flagS0,
                                           cnts, l1s, l1t);
    k_passD<<<edgeBlocks, TB, 0, stream>>>((const int4*)dst, nvec, flagS0, deg);
    k_conv1<<<listBlocks, TB, 0, stream>>>(cnts, l1s, l1t, x, W1, deg, acc1);
    k_h1<<<listBlocks, TB, 0, stream>>>(cnts, s1list, x, W1, b1, W2, deg, acc1, gB);
    k_conv2<<<listBlocks, TB, 0, stream>>>(cnts, l2s, l2t, gB, acc2);
    k_z<<<listBlocks, TB, 0, stream>>>(cnts, lt, b2, Wr, br, deg, acc2, gB, z);
    k_softmax<<<1, 64, 0, stream>>>(cnts, le, lt, z, out_score, out_tgt);
}

// Round 4
// 377.365 us; speedup vs baseline: 18.4829x; 2.4142x over previous
//
#include <hip/hip_runtime.h>

#define CAP_I   65536        // incident edges (expected ~64)
#define CAP_S1  (1 << 18)    // S1 nodes (expected ~2K)
#define CAP_L2  (1 << 20)    // edges into T (expected ~2K)
#define CAP_L1  (1 << 22)    // edges into S1 (expected ~64K)
#define LBUF    2048         // per-block LDS append buffer (entries)

// ---- pass A: stream src+dst, write default outputs, collect incident edges ----
__global__ void k_passA(const int4* __restrict__ src4, const int4* __restrict__ dst4, int nvec,
                        const int* __restrict__ nodep,
                        float4* __restrict__ out_score4, float4* __restrict__ out_tgt4,
                        int* __restrict__ cnts, int* __restrict__ le, int* __restrict__ lt) {
    int node = *nodep;
    int stride = gridDim.x * blockDim.x;
    const float4 zero = make_float4(0.f, 0.f, 0.f, 0.f);
    const float4 neg1 = make_float4(-1.f, -1.f, -1.f, -1.f);
    for (int v = blockIdx.x * blockDim.x + threadIdx.x; v < nvec; v += stride) {
        int4 s4 = src4[v];
        int4 d4 = dst4[v];
        out_score4[v] = zero;
        out_tgt4[v]   = neg1;
        int ss[4] = {s4.x, s4.y, s4.z, s4.w};
        int dd[4] = {d4.x, d4.y, d4.z, d4.w};
#pragma unroll
        for (int k = 0; k < 4; k++) {
            if (ss[k] == node || dd[k] == node) {
                int t = (ss[k] == node) ? dd[k] : ss[k];
                int pos = atomicAdd(&cnts[0], 1);
                if (pos < CAP_I) { le[pos] = v * 4 + k; lt[pos] = t; }
            }
        }
    }
}

// ---- mark T, seed S1/S0 with T ----
__global__ void k_markT(const int* __restrict__ cnts, const int* __restrict__ lt,
                        unsigned char* __restrict__ flagT, unsigned char* __restrict__ flagS1,
                        unsigned char* __restrict__ flagS0,
                        int* __restrict__ cnts_w, int* __restrict__ s1list) {
    int n = cnts[0]; if (n > CAP_I) n = CAP_I;
    for (int i = threadIdx.x; i < n; i += blockDim.x) {
        int t = lt[i];
        flagT[t] = 1; flagS0[t] = 1;
        if (!flagS1[t]) {                 // benign race: dup appends are harmless
            flagS1[t] = 1;
            int p = atomicAdd(&cnts_w[2], 1);
            if (p < CAP_S1) s1list[p] = t;
        }
    }
}

// ---- pass B: dst in T -> L2 edge list, srcs -> S1 (LDS-aggregated appends) ----
__global__ void k_passB(const int* __restrict__ src, const int4* __restrict__ dst4, int nvec,
                        const unsigned char* __restrict__ flagT,
                        unsigned char* __restrict__ flagS1, unsigned char* __restrict__ flagS0,
                        int* __restrict__ cnts, int* __restrict__ l2s, int* __restrict__ l2t,
                        int* __restrict__ s1list) {
    __shared__ int lcE, lcS, gbE, gbS;
    __shared__ int bes[LBUF], bet[LBUF], bs1[LBUF];
    if (threadIdx.x == 0) { lcE = 0; lcS = 0; }
    __syncthreads();
    int tid0 = blockIdx.x * blockDim.x + threadIdx.x;
    int stride = gridDim.x * blockDim.x;
    int itersU = (nvec + stride - 1) / stride;
    for (int it = 0; it < itersU; ++it) {
        int v = tid0 + it * stride;
        if (v < nvec) {
            int4 d4 = dst4[v];
            int dd[4] = {d4.x, d4.y, d4.z, d4.w};
#pragma unroll
            for (int k = 0; k < 4; k++) {
                int d = dd[k];
                if (flagT[d]) {
                    int s = src[v * 4 + k];
                    int p = atomicAdd(&lcE, 1);
                    if (p < LBUF) { bes[p] = s; bet[p] = d; }
                    if (!flagS1[s]) {     // benign race
                        flagS1[s] = 1; flagS0[s] = 1;
                        int q = atomicAdd(&lcS, 1);
                        if (q < LBUF) bs1[q] = s;
                    }
                }
            }
        }
        __syncthreads();
        if (lcE > LBUF - 1100 || lcS > LBUF - 1100) {   // rare flush
            int nE = min(lcE, LBUF), nS = min(lcS, LBUF);
            if (threadIdx.x == 0) {
                gbE = atomicAdd(&cnts[1], nE);
                gbS = atomicAdd(&cnts[2], nS);
            }
            __syncthreads();
            for (int i = threadIdx.x; i < nE; i += blockDim.x) {
                int pos = gbE + i;
                if (pos < CAP_L2) { l2s[pos] = bes[i]; l2t[pos] = bet[i]; }
            }
            for (int i = threadIdx.x; i < nS; i += blockDim.x) {
                int pos = gbS + i;
                if (pos < CAP_S1) s1list[pos] = bs1[i];
            }
            __syncthreads();
            if (threadIdx.x == 0) { lcE = 0; lcS = 0; }
        }
        __syncthreads();
    }
    int nE = min(lcE, LBUF), nS = min(lcS, LBUF);
    if (nE > 0 || nS > 0) {
        if (threadIdx.x == 0) {
            gbE = atomicAdd(&cnts[1], nE);
            gbS = atomicAdd(&cnts[2], nS);
        }
        __syncthreads();
        for (int i = threadIdx.x; i < nE; i += blockDim.x) {
            int pos = gbE + i;
            if (pos < CAP_L2) { l2s[pos] = bes[i]; l2t[pos] = bet[i]; }
        }
        for (int i = threadIdx.x; i < nS; i += blockDim.x) {
            int pos = gbS + i;
            if (pos < CAP_S1) s1list[pos] = bs1[i];
        }
    }
}

// ---- pass C: dst in S1 -> L1 edge list, srcs -> S0 (LDS-aggregated appends) ----
__global__ void k_passC(const int* __restrict__ src, const int4* __restrict__ dst4, int nvec,
                        const unsigned char* __restrict__ flagS1,
                        unsigned char* __restrict__ flagS0,
                        int* __restrict__ cnts, int* __restrict__ l1s, int* __restrict__ l1t) {
    __shared__ int lcnt, gbase;
    __shared__ int lbs[LBUF], lbt[LBUF];
    if (threadIdx.x == 0) lcnt = 0;
    __syncthreads();
    int tid0 = blockIdx.x * blockDim.x + threadIdx.x;
    int stride = gridDim.x * blockDim.x;
    int itersU = (nvec + stride - 1) / stride;
    for (int it = 0; it < itersU; ++it) {
        int v = tid0 + it * stride;
        if (v < nvec) {
            int4 d4 = dst4[v];
            int dd[4] = {d4.x, d4.y, d4.z, d4.w};
#pragma unroll
            for (int k = 0; k < 4; k++) {
                int d = dd[k];
                if (flagS1[d]) {
                    int s = src[v * 4 + k];
                    flagS0[s] = 1;
                    int p = atomicAdd(&lcnt, 1);   // LDS atomic
                    if (p < LBUF) { lbs[p] = s; lbt[p] = d; }
                }
            }
        }
        __syncthreads();
        if (lcnt > LBUF - 1100) {                  // rare flush, no-drop guarantee
            int n = min(lcnt, LBUF);
            if (threadIdx.x == 0) gbase = atomicAdd(&cnts[3], n);
            __syncthreads();
            for (int i = threadIdx.x; i < n; i += blockDim.x) {
                int pos = gbase + i;
                if (pos < CAP_L1) { l1s[pos] = lbs[i]; l1t[pos] = lbt[i]; }
            }
            __syncthreads();
            if (threadIdx.x == 0) lcnt = 0;
        }
        __syncthreads();
    }
    int n = min(lcnt, LBUF);
    if (n > 0) {
        if (threadIdx.x == 0) gbase = atomicAdd(&cnts[3], n);
        __syncthreads();
        for (int i = threadIdx.x; i < n; i += blockDim.x) {
            int pos = gbase + i;
            if (pos < CAP_L1) { l1s[pos] = lbs[i]; l1t[pos] = lbt[i]; }
        }
    }
}

// ---- pass D: in-degree, restricted to S0 ----
__global__ void k_passD(const int4* __restrict__ dst4, int nvec,
                        const unsigned char* __restrict__ flagS0, int* __restrict__ deg) {
    int stride = gridDim.x * blockDim.x;
    for (int v = blockIdx.x * blockDim.x + threadIdx.x; v < nvec; v += stride) {
        int4 d4 = dst4[v];
        int dd[4] = {d4.x, d4.y, d4.z, d4.w};
#pragma unroll
        for (int k = 0; k < 4; k++) {
            int d = dd[k];
            if (flagS0[d]) atomicAdd(&deg[d], 1);
        }
    }
}

// ---- conv1 accumulation over L1: acc1[d] += (x[s]@W1)*dinv[s] ----
__global__ void k_conv1(const int* __restrict__ cnts, const int* __restrict__ l1s,
                        const int* __restrict__ l1t, const float* __restrict__ x,
                        const float* __restrict__ W1, const int* __restrict__ deg,
                        float* __restrict__ acc1) {
    int n = cnts[3]; if (n > CAP_L1) n = CAP_L1;
    int stride = gridDim.x * blockDim.x;
    for (int j = blockIdx.x * blockDim.x + threadIdx.x; j < n; j += stride) {
        int s = l1s[j], d = l1t[j];
        float4 xv = *(const float4*)(x + (size_t)s * 4);
        float dis = rsqrtf((float)deg[s] + 1.0f);
        float o0 = (xv.x * W1[0] + xv.y * W1[4] + xv.z * W1[8]  + xv.w * W1[12]) * dis;
        float o1 = (xv.x * W1[1] + xv.y * W1[5] + xv.z * W1[9]  + xv.w * W1[13]) * dis;
        float o2 = (xv.x * W1[2] + xv.y * W1[6] + xv.z * W1[10] + xv.w * W1[14]) * dis;
        float o3 = (xv.x * W1[3] + xv.y * W1[7] + xv.z * W1[11] + xv.w * W1[15]) * dis;
        float* a = acc1 + (size_t)d * 4;
        atomicAdd(a + 0, o0); atomicAdd(a + 1, o1);
        atomicAdd(a + 2, o2); atomicAdd(a + 3, o3);
    }
}

// ---- h1 epilogue over S1: gB[i] = (relu(conv1_out)@W2)*dinv[i] ----
__global__ void k_h1(const int* __restrict__ cnts, const int* __restrict__ s1list,
                     const float* __restrict__ x, const float* __restrict__ W1,
                     const float* __restrict__ b1, const float* __restrict__ W2,
                     const int* __restrict__ deg, const float* __restrict__ acc1,
                     float* __restrict__ gB) {
    int n = cnts[2]; if (n > CAP_S1) n = CAP_S1;
    int stride = gridDim.x * blockDim.x;
    for (int j = blockIdx.x * blockDim.x + threadIdx.x; j < n; j += stride) {
        int i = s1list[j];
        float di = rsqrtf((float)deg[i] + 1.0f);
        float4 xv = *(const float4*)(x + (size_t)i * 4);
        float4 a  = *(const float4*)(acc1 + (size_t)i * 4);
        float w0 = xv.x * W1[0] + xv.y * W1[4] + xv.z * W1[8]  + xv.w * W1[12];
        float w1 = xv.x * W1[1] + xv.y * W1[5] + xv.z * W1[9]  + xv.w * W1[13];
        float w2 = xv.x * W1[2] + xv.y * W1[6] + xv.z * W1[10] + xv.w * W1[14];
        float w3 = xv.x * W1[3] + xv.y * W1[7] + xv.z * W1[11] + xv.w * W1[15];
        float h0 = fmaxf((a.x + w0 * di) * di + b1[0], 0.f);
        float h1 = fmaxf((a.y + w1 * di) * di + b1[1], 0.f);
        float h2 = fmaxf((a.z + w2 * di) * di + b1[2], 0.f);
        float h3 = fmaxf((a.w + w3 * di) * di + b1[3], 0.f);
        float4 o;
        o.x = (h0 * W2[0] + h1 * W2[4] + h2 * W2[8]  + h3 * W2[12]) * di;
        o.y = (h0 * W2[1] + h1 * W2[5] + h2 * W2[9]  + h3 * W2[13]) * di;
        o.z = (h0 * W2[2] + h1 * W2[6] + h2 * W2[10] + h3 * W2[14]) * di;
        o.w = (h0 * W2[3] + h1 * W2[7] + h2 * W2[11] + h3 * W2[15]) * di;
        *(float4*)(gB + (size_t)i * 4) = o;
    }
}

// ---- conv2 accumulation over L2: acc2[t] += gB[s] ----
__global__ void k_conv2(const int* __restrict__ cnts, const int* __restrict__ l2s,
                        const int* __restrict__ l2t, const float* __restrict__ gB,
                        float* __restrict__ acc2) {
    int n = cnts[1]; if (n > CAP_L2) n = CAP_L2;
    int stride = gridDim.x * blockDim.x;
    for (int j = blockIdx.x * blockDim.x + threadIdx.x; j < n; j += stride) {
        int s = l2s[j], t = l2t[j];
        float4 g = *(const float4*)(gB + (size_t)s * 4);
        float* a = acc2 + (size_t)t * 4;
        atomicAdd(a + 0, g.x); atomicAdd(a + 1, g.y);
        atomicAdd(a + 2, g.z); atomicAdd(a + 3, g.w);
    }
}

// ---- z epilogue over incident-target list ----
__global__ void k_z(const int* __restrict__ cnts, const int* __restrict__ lt,
                    const float* __restrict__ b2, const float* __restrict__ Wr,
                    const float* __restrict__ br, const int* __restrict__ deg,
                    const float* __restrict__ acc2, const float* __restrict__ gB,
                    float* __restrict__ z) {
    int n = cnts[0]; if (n > CAP_I) n = CAP_I;
    int stride = gridDim.x * blockDim.x;
    for (int j = blockIdx.x * blockDim.x + threadIdx.x; j < n; j += stride) {
        int t = lt[j];
        float di = rsqrtf((float)deg[t] + 1.0f);
        float4 a = *(const float4*)(acc2 + (size_t)t * 4);
        float4 g = *(const float4*)(gB + (size_t)t * 4);
        float h0 = fmaxf((a.x + g.x) * di + b2[0], 0.f);
        float h1 = fmaxf((a.y + g.y) * di + b2[1], 0.f);
        float h2 = fmaxf((a.z + g.z) * di + b2[2], 0.f);
        float h3 = fmaxf((a.w + g.w) * di + b2[3], 0.f);
        z[t] = h0 * Wr[0] + h1 * Wr[1] + h2 * Wr[2] + h3 * Wr[3] + br[0];
    }
}

// ---- tiny softmax over incident edges ----
__global__ void k_softmax(const int* __restrict__ cnts, const int* __restrict__ le,
                          const int* __restrict__ lt, const float* __restrict__ z,
                          float* __restrict__ out_score, float* __restrict__ out_tgt) {
    if (blockIdx.x != 0 || threadIdx.x != 0) return;
    int n = cnts[0]; if (n > CAP_I) n = CAP_I;
    float m = -3.402823466e+38f;
    for (int k = 0; k < n; k++) m = fmaxf(m, z[lt[k]]);
    float ssum = 0.f;
    for (int k = 0; k < n; k++) ssum += __expf(z[lt[k]] - m);
    float inv = (ssum > 0.f) ? 1.f / ssum : 0.f;
    for (int k = 0; k < n; k++) {
        out_score[le[k]] = __expf(z[lt[k]] - m) * inv;
        out_tgt[le[k]]   = (float)lt[k];
    }
}

extern "C" void kernel_launch(void* const* d_in, const int* in_sizes, int n_in,
                              void* d_out, int out_size, void* d_ws, size_t ws_size,
                              hipStream_t stream) {
    const float* x  = (const float*)d_in[0];
    const int*   ei = (const int*)d_in[1];
    const int*   nodep = (const int*)d_in[2];
    const float* W1 = (const float*)d_in[3];
    const float* b1 = (const float*)d_in[4];
    const float* W2 = (const float*)d_in[5];
    const float* b2 = (const float*)d_in[6];
    const float* Wr = (const float*)d_in[7];
    const float* br = (const float*)d_in[8];

    const int N = in_sizes[0] / 4;
    const int E = in_sizes[1] / 2;
    const int nvec = E / 4;
    const int* src = ei;
    const int* dst = ei + E;

    char* ws = (char*)d_ws;
    size_t off = 0;
    auto alloc = [&](size_t bytes) { char* p = ws + off; off = (off + bytes + 255) & ~(size_t)255; return p; };
    const size_t Npad = ((size_t)N + 255) & ~(size_t)255;
    int*   deg    = (int*)  alloc((size_t)N * 4);
    float* acc1   = (float*)alloc((size_t)N * 16);
    float* acc2   = (float*)alloc((size_t)N * 16);
    float* gB     = (float*)alloc((size_t)N * 16);
    float* z      = (float*)alloc((size_t)N * 4);
    unsigned char* flags = (unsigned char*)alloc(Npad * 3);   // T | S1 | S0, contiguous
    unsigned char* flagT  = flags;
    unsigned char* flagS1 = flags + Npad;
    unsigned char* flagS0 = flags + Npad * 2;
    int*   cnts   = (int*)  alloc(256);                 // [0]=I [1]=L2 [2]=S1 [3]=L1
    int*   le     = (int*)  alloc((size_t)CAP_I * 4);
    int*   lt     = (int*)  alloc((size_t)CAP_I * 4);
    int*   s1list = (int*)  alloc((size_t)CAP_S1 * 4);
    int*   l2s    = (int*)  alloc((size_t)CAP_L2 * 4);
    int*   l2t    = (int*)  alloc((size_t)CAP_L2 * 4);
    int*   l1s    = (int*)  alloc((size_t)CAP_L1 * 4);
    int*   l1t    = (int*)  alloc((size_t)CAP_L1 * 4);

    float* out_score = (float*)d_out;
    float* out_tgt   = out_score + E;

    const int TB = 256;
    int edgeBlocks = (nvec + TB - 1) / TB;
    if (edgeBlocks > 2048) edgeBlocks = 2048;
    const int listBlocks = 256;

    hipMemsetAsync(deg,  0, (size_t)N * 4, stream);
    hipMemsetAsync(acc1, 0, (size_t)N * 16, stream);
    hipMemsetAsync(acc2, 0, (size_t)N * 16, stream);
    hipMemsetAsync(flags, 0, Npad * 3, stream);
    hipMemsetAsync(cnts, 0, 256, stream);

    k_passA<<<edgeBlocks, TB, 0, stream>>>((const int4*)src, (const int4*)dst, nvec, nodep,
                                           (float4*)out_score, (float4*)out_tgt, cnts, le, lt);
    k_markT<<<1, 256, 0, stream>>>(cnts, lt, flagT, flagS1, flagS0, cnts, s1list);
    k_passB<<<edgeBlocks, TB, 0, stream>>>(src, (const int4*)dst, nvec, flagT, flagS1, flagS0,
                                           cnts, l2s, l2t, s1list);
    k_passC<<<edgeBlocks, TB, 0, stream>>>(src, (const int4*)dst, nvec, flagS1, flagS0,
                                           cnts, l1s, l1t);
    k_passD<<<edgeBlocks, TB, 0, stream>>>((const int4*)dst, nvec, flagS0, deg);
    k_conv1<<<listBlocks, TB, 0, stream>>>(cnts, l1s, l1t, x, W1, deg, acc1);
    k_h1<<<listBlocks, TB, 0, stream>>>(cnts, s1list, x, W1, b1, W2, deg, acc1, gB);
    k_conv2<<<listBlocks, TB, 0, stream>>>(cnts, l2s, l2t, gB, acc2);
    k_z<<<listBlocks, TB, 0, stream>>>(cnts, lt, b2, Wr, br, deg, acc2, gB, z);
    k_softmax<<<1, 64, 0, stream>>>(cnts, le, lt, z, out_score, out_tgt);
}

// Round 5
// 303.373 us; speedup vs baseline: 22.9908x; 1.2439x over previous
//
#include <hip/hip_runtime.h>

#define CAP_I   65536        // incident edges (expected ~64)
#define CAP_S1  (1 << 18)    // S1 nodes (expected ~2K)
#define CAP_L2  (1 << 20)    // edges into T (expected ~2K)
#define CAP_L1  (1 << 22)    // edges into S1 (expected ~64K)
#define LBUF    2560         // per-block LDS append buffer (entries)
#define FLUSH_THRESH 512     // LBUF - FLUSH_THRESH >= 512 threads * 4 edges
#define NWMAX   15680        // bitmap words: supports N <= 501,760

typedef unsigned int uint;

// ---- pass A: stream src+dst, write default outputs, collect incident edges ----
__global__ void k_passA(const int4* __restrict__ src4, const int4* __restrict__ dst4, int nvec,
                        const int* __restrict__ nodep,
                        float4* __restrict__ out_score4, float4* __restrict__ out_tgt4,
                        int* __restrict__ cnts, int* __restrict__ le, int* __restrict__ lt) {
    int node = *nodep;
    int stride = gridDim.x * blockDim.x;
    const float4 zero = make_float4(0.f, 0.f, 0.f, 0.f);
    const float4 neg1 = make_float4(-1.f, -1.f, -1.f, -1.f);
    for (int v = blockIdx.x * blockDim.x + threadIdx.x; v < nvec; v += stride) {
        int4 s4 = src4[v];
        int4 d4 = dst4[v];
        out_score4[v] = zero;
        out_tgt4[v]   = neg1;
        int ss[4] = {s4.x, s4.y, s4.z, s4.w};
        int dd[4] = {d4.x, d4.y, d4.z, d4.w};
#pragma unroll
        for (int k = 0; k < 4; k++) {
            if (ss[k] == node || dd[k] == node) {
                int t = (ss[k] == node) ? dd[k] : ss[k];
                int pos = atomicAdd(&cnts[0], 1);
                if (pos < CAP_I) { le[pos] = v * 4 + k; lt[pos] = t; }
            }
        }
    }
}

// ---- mark T in bitmaps, seed S1/S0 with T ----
__global__ void k_markT(const int* __restrict__ cnts, const int* __restrict__ lt,
                        uint* __restrict__ bmT, uint* __restrict__ bmS1,
                        uint* __restrict__ bmS0,
                        int* __restrict__ cnts_w, int* __restrict__ s1list) {
    int n = cnts[0]; if (n > CAP_I) n = CAP_I;
    for (int i = threadIdx.x; i < n; i += blockDim.x) {
        int t = lt[i];
        uint bit = 1u << (t & 31);
        atomicOr(&bmT[t >> 5], bit);
        uint old = atomicOr(&bmS1[t >> 5], bit);
        if (!(old & bit)) {
            atomicOr(&bmS0[t >> 5], bit);
            int p = atomicAdd(&cnts_w[2], 1);
            if (p < CAP_S1) s1list[p] = t;
        }
    }
}

// ---- pass B: dst in T -> L2 edge list, srcs -> S1 (LDS bitmap + LDS appends) ----
__global__ __launch_bounds__(512) void k_passB(
        const int* __restrict__ src, const int4* __restrict__ dst4, int nvec, int NW,
        const uint* __restrict__ bmT, uint* __restrict__ bmS1, uint* __restrict__ bmS0,
        int* __restrict__ cnts, int* __restrict__ l2s, int* __restrict__ l2t,
        int* __restrict__ s1list) {
    __shared__ uint lT[NWMAX];
    __shared__ int bes[LBUF], bet[LBUF], bs1[LBUF];
    __shared__ int lcE, lcS, gbE, gbS;
    for (int i = threadIdx.x; i < NW; i += blockDim.x) lT[i] = bmT[i];
    if (threadIdx.x == 0) { lcE = 0; lcS = 0; }
    __syncthreads();
    int tid0 = blockIdx.x * blockDim.x + threadIdx.x;
    int stride = gridDim.x * blockDim.x;
    int itersU = (nvec + stride - 1) / stride;
    for (int it = 0; it < itersU; ++it) {
        int v = tid0 + it * stride;
        if (v < nvec) {
            int4 d4 = dst4[v];
            int dd[4] = {d4.x, d4.y, d4.z, d4.w};
#pragma unroll
            for (int k = 0; k < 4; k++) {
                int d = dd[k];
                if ((lT[d >> 5] >> (d & 31)) & 1u) {
                    int s = src[v * 4 + k];
                    int p = atomicAdd(&lcE, 1);
                    if (p < LBUF) { bes[p] = s; bet[p] = d; }
                    uint bit = 1u << (s & 31);
                    uint old = atomicOr(&bmS1[s >> 5], bit);
                    if (!(old & bit)) {
                        atomicOr(&bmS0[s >> 5], bit);
                        int q = atomicAdd(&lcS, 1);
                        if (q < LBUF) bs1[q] = s;
                    }
                }
            }
        }
        __syncthreads();
        if (lcE > FLUSH_THRESH || lcS > FLUSH_THRESH) {
            int nE = min(lcE, LBUF), nS = min(lcS, LBUF);
            if (threadIdx.x == 0) {
                gbE = atomicAdd(&cnts[1], nE);
                gbS = atomicAdd(&cnts[2], nS);
            }
            __syncthreads();
            for (int i = threadIdx.x; i < nE; i += blockDim.x) {
                int pos = gbE + i;
                if (pos < CAP_L2) { l2s[pos] = bes[i]; l2t[pos] = bet[i]; }
            }
            for (int i = threadIdx.x; i < nS; i += blockDim.x) {
                int pos = gbS + i;
                if (pos < CAP_S1) s1list[pos] = bs1[i];
            }
            __syncthreads();
            if (threadIdx.x == 0) { lcE = 0; lcS = 0; }
        }
        __syncthreads();
    }
    int nE = min(lcE, LBUF), nS = min(lcS, LBUF);
    if (nE > 0 || nS > 0) {
        if (threadIdx.x == 0) {
            gbE = atomicAdd(&cnts[1], nE);
            gbS = atomicAdd(&cnts[2], nS);
        }
        __syncthreads();
        for (int i = threadIdx.x; i < nE; i += blockDim.x) {
            int pos = gbE + i;
            if (pos < CAP_L2) { l2s[pos] = bes[i]; l2t[pos] = bet[i]; }
        }
        for (int i = threadIdx.x; i < nS; i += blockDim.x) {
            int pos = gbS + i;
            if (pos < CAP_S1) s1list[pos] = bs1[i];
        }
    }
}

// ---- pass C: dst in S1 -> L1 edge list, srcs -> S0 (LDS bitmap + LDS appends) ----
__global__ __launch_bounds__(512) void k_passC(
        const int* __restrict__ src, const int4* __restrict__ dst4, int nvec, int NW,
        const uint* __restrict__ bmS1, uint* __restrict__ bmS0,
        int* __restrict__ cnts, int* __restrict__ l1s, int* __restrict__ l1t) {
    __shared__ uint lS1[NWMAX];
    __shared__ int lbs[LBUF], lbt[LBUF];
    __shared__ int lcnt, gbase;
    for (int i = threadIdx.x; i < NW; i += blockDim.x) lS1[i] = bmS1[i];
    if (threadIdx.x == 0) lcnt = 0;
    __syncthreads();
    int tid0 = blockIdx.x * blockDim.x + threadIdx.x;
    int stride = gridDim.x * blockDim.x;
    int itersU = (nvec + stride - 1) / stride;
    for (int it = 0; it < itersU; ++it) {
        int v = tid0 + it * stride;
        if (v < nvec) {
            int4 d4 = dst4[v];
            int dd[4] = {d4.x, d4.y, d4.z, d4.w};
#pragma unroll
            for (int k = 0; k < 4; k++) {
                int d = dd[k];
                if ((lS1[d >> 5] >> (d & 31)) & 1u) {
                    int s = src[v * 4 + k];
                    atomicOr(&bmS0[s >> 5], 1u << (s & 31));
                    int p = atomicAdd(&lcnt, 1);
                    if (p < LBUF) { lbs[p] = s; lbt[p] = d; }
                }
            }
        }
        __syncthreads();
        if (lcnt > FLUSH_THRESH) {
            int n = min(lcnt, LBUF);
            if (threadIdx.x == 0) gbase = atomicAdd(&cnts[3], n);
            __syncthreads();
            for (int i = threadIdx.x; i < n; i += blockDim.x) {
                int pos = gbase + i;
                if (pos < CAP_L1) { l1s[pos] = lbs[i]; l1t[pos] = lbt[i]; }
            }
            __syncthreads();
            if (threadIdx.x == 0) lcnt = 0;
        }
        __syncthreads();
    }
    int n = min(lcnt, LBUF);
    if (n > 0) {
        if (threadIdx.x == 0) gbase = atomicAdd(&cnts[3], n);
        __syncthreads();
        for (int i = threadIdx.x; i < n; i += blockDim.x) {
            int pos = gbase + i;
            if (pos < CAP_L1) { l1s[pos] = lbs[i]; l1t[pos] = lbt[i]; }
        }
    }
}

// ---- pass D: in-degree restricted to S0 (LDS bitmap) ----
__global__ __launch_bounds__(512) void k_passD(
        const int4* __restrict__ dst4, int nvec, int NW,
        const uint* __restrict__ bmS0, int* __restrict__ deg) {
    __shared__ uint lS0[NWMAX];
    for (int i = threadIdx.x; i < NW; i += blockDim.x) lS0[i] = bmS0[i];
    __syncthreads();
    int stride = gridDim.x * blockDim.x;
    for (int v = blockIdx.x * blockDim.x + threadIdx.x; v < nvec; v += stride) {
        int4 d4 = dst4[v];
        int dd[4] = {d4.x, d4.y, d4.z, d4.w};
#pragma unroll
        for (int k = 0; k < 4; k++) {
            int d = dd[k];
            if ((lS0[d >> 5] >> (d & 31)) & 1u) atomicAdd(&deg[d], 1);
        }
    }
}

// ---- conv1 accumulation over L1: acc1[d] += (x[s]@W1)*dinv[s] ----
__global__ void k_conv1(const int* __restrict__ cnts, const int* __restrict__ l1s,
                        const int* __restrict__ l1t, const float* __restrict__ x,
                        const float* __restrict__ W1, const int* __restrict__ deg,
                        float* __restrict__ acc1) {
    int n = cnts[3]; if (n > CAP_L1) n = CAP_L1;
    int stride = gridDim.x * blockDim.x;
    for (int j = blockIdx.x * blockDim.x + threadIdx.x; j < n; j += stride) {
        int s = l1s[j], d = l1t[j];
        float4 xv = *(const float4*)(x + (size_t)s * 4);
        float dis = rsqrtf((float)deg[s] + 1.0f);
        float o0 = (xv.x * W1[0] + xv.y * W1[4] + xv.z * W1[8]  + xv.w * W1[12]) * dis;
        float o1 = (xv.x * W1[1] + xv.y * W1[5] + xv.z * W1[9]  + xv.w * W1[13]) * dis;
        float o2 = (xv.x * W1[2] + xv.y * W1[6] + xv.z * W1[10] + xv.w * W1[14]) * dis;
        float o3 = (xv.x * W1[3] + xv.y * W1[7] + xv.z * W1[11] + xv.w * W1[15]) * dis;
        float* a = acc1 + (size_t)d * 4;
        atomicAdd(a + 0, o0); atomicAdd(a + 1, o1);
        atomicAdd(a + 2, o2); atomicAdd(a + 3, o3);
    }
}

// ---- h1 epilogue over S1: gB[i] = (relu(conv1_out)@W2)*dinv[i] ----
__global__ void k_h1(const int* __restrict__ cnts, const int* __restrict__ s1list,
                     const float* __restrict__ x, const float* __restrict__ W1,
                     const float* __restrict__ b1, const float* __restrict__ W2,
                     const int* __restrict__ deg, const float* __restrict__ acc1,
                     float* __restrict__ gB) {
    int n = cnts[2]; if (n > CAP_S1) n = CAP_S1;
    int stride = gridDim.x * blockDim.x;
    for (int j = blockIdx.x * blockDim.x + threadIdx.x; j < n; j += stride) {
        int i = s1list[j];
        float di = rsqrtf((float)deg[i] + 1.0f);
        float4 xv = *(const float4*)(x + (size_t)i * 4);
        float4 a  = *(const float4*)(acc1 + (size_t)i * 4);
        float w0 = xv.x * W1[0] + xv.y * W1[4] + xv.z * W1[8]  + xv.w * W1[12];
        float w1 = xv.x * W1[1] + xv.y * W1[5] + xv.z * W1[9]  + xv.w * W1[13];
        float w2 = xv.x * W1[2] + xv.y * W1[6] + xv.z * W1[10] + xv.w * W1[14];
        float w3 = xv.x * W1[3] + xv.y * W1[7] + xv.z * W1[11] + xv.w * W1[15];
        float h0 = fmaxf((a.x + w0 * di) * di + b1[0], 0.f);
        float h1 = fmaxf((a.y + w1 * di) * di + b1[1], 0.f);
        float h2 = fmaxf((a.z + w2 * di) * di + b1[2], 0.f);
        float h3 = fmaxf((a.w + w3 * di) * di + b1[3], 0.f);
        float4 o;
        o.x = (h0 * W2[0] + h1 * W2[4] + h2 * W2[8]  + h3 * W2[12]) * di;
        o.y = (h0 * W2[1] + h1 * W2[5] + h2 * W2[9]  + h3 * W2[13]) * di;
        o.z = (h0 * W2[2] + h1 * W2[6] + h2 * W2[10] + h3 * W2[14]) * di;
        o.w = (h0 * W2[3] + h1 * W2[7] + h2 * W2[11] + h3 * W2[15]) * di;
        *(float4*)(gB + (size_t)i * 4) = o;
    }
}

// ---- conv2 accumulation over L2: acc2[t] += gB[s] ----
__global__ void k_conv2(const int* __restrict__ cnts, const int* __restrict__ l2s,
                        const int* __restrict__ l2t, const float* __restrict__ gB,
                        float* __restrict__ acc2) {
    int n = cnts[1]; if (n > CAP_L2) n = CAP_L2;
    int stride = gridDim.x * blockDim.x;
    for (int j = blockIdx.x * blockDim.x + threadIdx.x; j < n; j += stride) {
        int s = l2s[j], t = l2t[j];
        float4 g = *(const float4*)(gB + (size_t)s * 4);
        float* a = acc2 + (size_t)t * 4;
        atomicAdd(a + 0, g.x); atomicAdd(a + 1, g.y);
        atomicAdd(a + 2, g.z); atomicAdd(a + 3, g.w);
    }
}

// ---- z epilogue over incident-target list ----
__global__ void k_z(const int* __restrict__ cnts, const int* __restrict__ lt,
                    const float* __restrict__ b2, const float* __restrict__ Wr,
                    const float* __restrict__ br, const int* __restrict__ deg,
                    const float* __restrict__ acc2, const float* __restrict__ gB,
                    float* __restrict__ z) {
    int n = cnts[0]; if (n > CAP_I) n = CAP_I;
    int stride = gridDim.x * blockDim.x;
    for (int j = blockIdx.x * blockDim.x + threadIdx.x; j < n; j += stride) {
        int t = lt[j];
        float di = rsqrtf((float)deg[t] + 1.0f);
        float4 a = *(const float4*)(acc2 + (size_t)t * 4);
        float4 g = *(const float4*)(gB + (size_t)t * 4);
        float h0 = fmaxf((a.x + g.x) * di + b2[0], 0.f);
        float h1 = fmaxf((a.y + g.y) * di + b2[1], 0.f);
        float h2 = fmaxf((a.z + g.z) * di + b2[2], 0.f);
        float h3 = fmaxf((a.w + g.w) * di + b2[3], 0.f);
        z[t] = h0 * Wr[0] + h1 * Wr[1] + h2 * Wr[2] + h3 * Wr[3] + br[0];
    }
}

// ---- tiny softmax over incident edges ----
__global__ void k_softmax(const int* __restrict__ cnts, const int* __restrict__ le,
                          const int* __restrict__ lt, const float* __restrict__ z,
                          float* __restrict__ out_score, float* __restrict__ out_tgt) {
    if (blockIdx.x != 0 || threadIdx.x != 0) return;
    int n = cnts[0]; if (n > CAP_I) n = CAP_I;
    float m = -3.402823466e+38f;
    for (int k = 0; k < n; k++) m = fmaxf(m, z[lt[k]]);
    float ssum = 0.f;
    for (int k = 0; k < n; k++) ssum += __expf(z[lt[k]] - m);
    float inv = (ssum > 0.f) ? 1.f / ssum : 0.f;
    for (int k = 0; k < n; k++) {
        out_score[le[k]] = __expf(z[lt[k]] - m) * inv;
        out_tgt[le[k]]   = (float)lt[k];
    }
}

extern "C" void kernel_launch(void* const* d_in, const int* in_sizes, int n_in,
                              void* d_out, int out_size, void* d_ws, size_t ws_size,
                              hipStream_t stream) {
    const float* x  = (const float*)d_in[0];
    const int*   ei = (const int*)d_in[1];
    const int*   nodep = (const int*)d_in[2];
    const float* W1 = (const float*)d_in[3];
    const float* b1 = (const float*)d_in[4];
    const float* W2 = (const float*)d_in[5];
    const float* b2 = (const float*)d_in[6];
    const float* Wr = (const float*)d_in[7];
    const float* br = (const float*)d_in[8];

    const int N = in_sizes[0] / 4;
    const int E = in_sizes[1] / 2;
    const int nvec = E / 4;
    const int NW = (N + 31) / 32;          // bitmap words (<= NWMAX for N<=501,760)
    const int* src = ei;
    const int* dst = ei + E;

    char* ws = (char*)d_ws;
    size_t off = 0;
    auto alloc = [&](size_t bytes) { char* p = ws + off; off = (off + bytes + 255) & ~(size_t)255; return p; };
    // ---- contiguous zeroed region ----
    char* zero_base = ws;
    int*   deg    = (int*)  alloc((size_t)N * 4);
    float* acc1   = (float*)alloc((size_t)N * 16);
    float* acc2   = (float*)alloc((size_t)N * 16);
    uint*  bmT    = (uint*) alloc((size_t)NW * 4);
    uint*  bmS1   = (uint*) alloc((size_t)NW * 4);
    uint*  bmS0   = (uint*) alloc((size_t)NW * 4);
    int*   cnts   = (int*)  alloc(256);                 // [0]=I [1]=L2 [2]=S1 [3]=L1
    size_t zero_len = off;
    // ---- non-zeroed ----
    float* gB     = (float*)alloc((size_t)N * 16);
    float* z      = (float*)alloc((size_t)N * 4);
    int*   le     = (int*)  alloc((size_t)CAP_I * 4);
    int*   lt     = (int*)  alloc((size_t)CAP_I * 4);
    int*   s1list = (int*)  alloc((size_t)CAP_S1 * 4);
    int*   l2s    = (int*)  alloc((size_t)CAP_L2 * 4);
    int*   l2t    = (int*)  alloc((size_t)CAP_L2 * 4);
    int*   l1s    = (int*)  alloc((size_t)CAP_L1 * 4);
    int*   l1t    = (int*)  alloc((size_t)CAP_L1 * 4);

    float* out_score = (float*)d_out;
    float* out_tgt   = out_score + E;

    int edgeBlocksA = (nvec + 255) / 256;
    if (edgeBlocksA > 2048) edgeBlocksA = 2048;
    const int listBlocks = 256;

    hipMemsetAsync(zero_base, 0, zero_len, stream);

    k_passA<<<edgeBlocksA, 256, 0, stream>>>((const int4*)src, (const int4*)dst, nvec, nodep,
                                             (float4*)out_score, (float4*)out_tgt, cnts, le, lt);
    k_markT<<<1, 256, 0, stream>>>(cnts, lt, bmT, bmS1, bmS0, cnts, s1list);
    k_passB<<<512, 512, 0, stream>>>(src, (const int4*)dst, nvec, NW, bmT, bmS1, bmS0,
                                     cnts, l2s, l2t, s1list);
    k_passC<<<512, 512, 0, stream>>>(src, (const int4*)dst, nvec, NW, bmS1, bmS0,
                                     cnts, l1s, l1t);
    k_passD<<<1024, 512, 0, stream>>>((const int4*)dst, nvec, NW, bmS0, deg);
    k_conv1<<<listBlocks, 256, 0, stream>>>(cnts, l1s, l1t, x, W1, deg, acc1);
    k_h1<<<listBlocks, 256, 0, stream>>>(cnts, s1list, x, W1, b1, W2, deg, acc1, gB);
    k_conv2<<<listBlocks, 256, 0, stream>>>(cnts, l2s, l2t, gB, acc2);
    k_z<<<listBlocks, 256, 0, stream>>>(cnts, lt, b2, Wr, br, deg, acc2, gB, z);
    k_softmax<<<1, 64, 0, stream>>>(cnts, le, lt, z, out_score, out_tgt);
}